// Round 1
// baseline (887.139 us; speedup 1.0000x reference)
//
#include <hip/hip_runtime.h>
#include <stdint.h>

#define M_DIM 8192
#define K_DIM 4096
#define N_DIM 4096
#define FP8_MAX 448.0f

typedef float floatx4 __attribute__((ext_vector_type(4)));

// ---------- helpers ----------

__device__ __forceinline__ uint32_t pack4_fp8(float a, float b, float c, float d) {
    // v_cvt_pk_fp8_f32: byte0=cvt(src0), byte1=cvt(src1); word=1 -> bytes 2,3
    int v = __builtin_amdgcn_cvt_pk_fp8_f32(a, b, 0, false);
    v = __builtin_amdgcn_cvt_pk_fp8_f32(c, d, v, true);
    return (uint32_t)v;
}

__device__ __forceinline__ void gload_lds16(const uint8_t* g, uint8_t* l) {
    __builtin_amdgcn_global_load_lds(
        (const __attribute__((address_space(1))) uint32_t*)g,
        (__attribute__((address_space(3))) uint32_t*)l,
        16, 0, 0);
}

__device__ __forceinline__ float scale_from_amax(float amax) {
    return FP8_MAX / fmaxf(amax, 1e-12f);
}

// ---------- kernel 0: init amax slots (ws is re-poisoned 0xAA each call) ----------

__global__ void init_amax_kernel(uint32_t* amax) {
    amax[0] = 0u;
    amax[1] = 0u;
}

// ---------- kernel 1: per-tensor amax (fp32, abs-max) ----------

__global__ void amax_kernel(const float* __restrict__ src, long n, uint32_t* out_bits) {
    long i = (long)blockIdx.x * blockDim.x + threadIdx.x;
    long stride = (long)gridDim.x * blockDim.x;
    const float4* s4 = (const float4*)src;
    long n4 = n >> 2;
    float m = 0.0f;
    for (long j = i; j < n4; j += stride) {
        float4 v = s4[j];
        m = fmaxf(m, fmaxf(fmaxf(fabsf(v.x), fabsf(v.y)), fmaxf(fabsf(v.z), fabsf(v.w))));
    }
    // wave64 reduce
    #pragma unroll
    for (int off = 32; off > 0; off >>= 1)
        m = fmaxf(m, __shfl_down(m, off, 64));
    __shared__ float smax[4];
    int wave = threadIdx.x >> 6;
    if ((threadIdx.x & 63) == 0) smax[wave] = m;
    __syncthreads();
    if (threadIdx.x == 0) {
        float bm = fmaxf(fmaxf(smax[0], smax[1]), fmaxf(smax[2], smax[3]));
        atomicMax(out_bits, __float_as_uint(bm));  // non-negative floats: bit order == value order
    }
}

// ---------- kernel 2: quantize x -> fp8 (row-major [M][K]) ----------

__global__ void quant_kernel(const float* __restrict__ src, uint8_t* __restrict__ dst,
                             long n, const uint32_t* __restrict__ amax_bits) {
    float scale = scale_from_amax(__uint_as_float(*amax_bits));
    long j = (long)blockIdx.x * blockDim.x + threadIdx.x;   // one 16-elem chunk per thread
    long n16 = n >> 4;
    if (j >= n16) return;
    const float4* s4 = (const float4*)src;
    float4 a = s4[j * 4 + 0];
    float4 b = s4[j * 4 + 1];
    float4 c = s4[j * 4 + 2];
    float4 d = s4[j * 4 + 3];
    uint4 o;
    o.x = pack4_fp8(a.x * scale, a.y * scale, a.z * scale, a.w * scale);
    o.y = pack4_fp8(b.x * scale, b.y * scale, b.z * scale, b.w * scale);
    o.z = pack4_fp8(c.x * scale, c.y * scale, c.z * scale, c.w * scale);
    o.w = pack4_fp8(d.x * scale, d.y * scale, d.z * scale, d.w * scale);
    ((uint4*)dst)[j] = o;
}

// ---------- kernel 3: quantize + transpose w [K][N] -> qwT fp8 [N][K] ----------

__global__ void quantT_kernel(const float* __restrict__ w, uint8_t* __restrict__ qt,
                              const uint32_t* __restrict__ amax_bits) {
    float scale = scale_from_amax(__uint_as_float(*amax_bits));
    __shared__ uint8_t tile[64][68];   // [k][o], padded stride breaks bank patterns
    int k0 = blockIdx.y * 64;
    int o0 = blockIdx.x * 64;
    int t = threadIdx.x;
    int f = t & 15;        // float4 / 4-byte chunk index within a 64-wide row
    int rbase = t >> 4;    // 0..15

    #pragma unroll
    for (int p = 0; p < 4; ++p) {
        int r = p * 16 + rbase;  // k index within tile
        float4 v = ((const float4*)(w + (long)(k0 + r) * N_DIM + o0))[f];
        uint32_t pk = pack4_fp8(v.x * scale, v.y * scale, v.z * scale, v.w * scale);
        *(uint32_t*)&tile[r][f * 4] = pk;
    }
    __syncthreads();
    #pragma unroll
    for (int p = 0; p < 4; ++p) {
        int o = p * 16 + rbase;  // output row (n index)
        int kc = f;              // 4-byte chunk along k
        uint32_t pk = (uint32_t)tile[kc * 4 + 0][o]
                    | ((uint32_t)tile[kc * 4 + 1][o] << 8)
                    | ((uint32_t)tile[kc * 4 + 2][o] << 16)
                    | ((uint32_t)tile[kc * 4 + 3][o] << 24);
        *(uint32_t*)(qt + (long)(o0 + o) * K_DIM + k0 + kc * 4) = pk;
    }
}

// ---------- kernel 4: fp8 MFMA GEMM: C[M][N] = (qx[M][K] . qwT[N][K]^T) * dq + bias ----------

#define BM 128
#define BN 128
#define BK 64

__global__ __launch_bounds__(256)
void gemm_kernel(const uint8_t* __restrict__ qx, const uint8_t* __restrict__ qwT,
                 const float* __restrict__ bias, float* __restrict__ C,
                 const uint32_t* __restrict__ amax_bits) {
    float sx = scale_from_amax(__uint_as_float(amax_bits[0]));
    float sw = scale_from_amax(__uint_as_float(amax_bits[1]));
    float dq = 1.0f / (sx * sw);

    __shared__ __align__(16) uint8_t sA[BM * BK];   // [row][k] rows of x-tile
    __shared__ __align__(16) uint8_t sB[BN * BK];   // [row][k] rows of wT-tile

    int tid = threadIdx.x;
    int wave = tid >> 6;
    int lane = tid & 63;

    long tileM = (long)blockIdx.y * BM;
    long tileN = (long)blockIdx.x * BN;

    const uint8_t* gA = qx + tileM * K_DIM;
    const uint8_t* gB = qwT + tileN * K_DIM;

    floatx4 acc[4][4];
    #pragma unroll
    for (int i = 0; i < 4; ++i)
        #pragma unroll
        for (int j = 0; j < 4; ++j)
            acc[i][j] = (floatx4)0.0f;

    int waveM = (wave >> 1) * 64;
    int waveN = (wave & 1) * 64;
    int am = waveM + (lane & 15);     // A row for mi=0
    int bn = waveN + (lane & 15);     // B row for ni=0
    int kq = (lane >> 4) * 8;         // per-lane K byte offset within a K=32 step

    for (int k0 = 0; k0 < K_DIM; k0 += BK) {
        __syncthreads();  // previous compute done before overwriting LDS
        // stage A and B tiles: 512 16B chunks each; chunk c -> row c/4, byte (c&3)*16
        #pragma unroll
        for (int it = 0; it < 2; ++it) {
            int c = tid + it * 256;
            int row = c >> 2;
            int off = (c & 3) * 16;
            gload_lds16(gA + (long)row * K_DIM + k0 + off, sA + c * 16);
            gload_lds16(gB + (long)row * K_DIM + k0 + off, sB + c * 16);
        }
        __syncthreads();  // staging visible (compiler drains vmcnt before barrier)

        #pragma unroll
        for (int kk = 0; kk < BK; kk += 32) {
            long aF[4], bF[4];
            #pragma unroll
            for (int mi = 0; mi < 4; ++mi)
                aF[mi] = *(const long*)(sA + (am + mi * 16) * BK + kk + kq);
            #pragma unroll
            for (int ni = 0; ni < 4; ++ni)
                bF[ni] = *(const long*)(sB + (bn + ni * 16) * BK + kk + kq);
            #pragma unroll
            for (int mi = 0; mi < 4; ++mi)
                #pragma unroll
                for (int ni = 0; ni < 4; ++ni)
                    acc[mi][ni] = __builtin_amdgcn_mfma_f32_16x16x32_fp8_fp8(
                        aF[mi], bF[ni], acc[mi][ni], 0, 0, 0);
        }
    }

    // epilogue: C[row][col] = acc * dq + bias[col]
    long colBase = tileN + waveN + (lane & 15);
    float bV[4];
    #pragma unroll
    for (int ni = 0; ni < 4; ++ni) bV[ni] = bias[colBase + ni * 16];

    #pragma unroll
    for (int mi = 0; mi < 4; ++mi) {
        #pragma unroll
        for (int r = 0; r < 4; ++r) {
            long row = tileM + waveM + mi * 16 + (lane >> 4) * 4 + r;
            float* crow = C + row * N_DIM;
            #pragma unroll
            for (int ni = 0; ni < 4; ++ni)
                crow[colBase + ni * 16] = acc[mi][ni][r] * dq + bV[ni];
        }
    }
}

// ---------- launch ----------

extern "C" void kernel_launch(void* const* d_in, const int* in_sizes, int n_in,
                              void* d_out, int out_size, void* d_ws, size_t ws_size,
                              hipStream_t stream) {
    const float* x = (const float*)d_in[0];     // [M][K]
    const float* w = (const float*)d_in[1];     // [K][N]
    const float* bias = (const float*)d_in[2];  // [N]
    float* out = (float*)d_out;                 // [M][N]

    uint32_t* amax = (uint32_t*)d_ws;           // [0]=amax_x, [1]=amax_w
    uint8_t* qx = (uint8_t*)d_ws + 256;
    uint8_t* qwT = qx + (size_t)M_DIM * K_DIM;

    init_amax_kernel<<<1, 64, 0, stream>>>(amax);
    amax_kernel<<<2048, 256, 0, stream>>>(x, (long)M_DIM * K_DIM, amax + 0);
    amax_kernel<<<1024, 256, 0, stream>>>(w, (long)K_DIM * N_DIM, amax + 1);
    quant_kernel<<<(int)(((long)M_DIM * K_DIM / 16 + 255) / 256), 256, 0, stream>>>(
        x, qx, (long)M_DIM * K_DIM, amax + 0);
    quantT_kernel<<<dim3(N_DIM / 64, K_DIM / 64), 256, 0, stream>>>(w, qwT, amax + 1);
    gemm_kernel<<<dim3(N_DIM / BN, M_DIM / BM), 256, 0, stream>>>(qx, qwT, bias, out, amax);
}

// Round 3
// 594.464 us; speedup vs baseline: 1.4923x; 1.4923x over previous
//
#include <hip/hip_runtime.h>
#include <stdint.h>

#define M_DIM 8192
#define K_DIM 4096
#define N_DIM 4096
#define FP8_MAX 448.0f

typedef float floatx4 __attribute__((ext_vector_type(4)));

// Tiled fp8 layout: tensor split into [128-row x 64-k] tiles of 8192 B.
// Tile (i = row/128, b = k/64) at byte offset (i*(K/64) + b)*8192.
// Within a tile, 8-byte granule (r = row%128, g = (k%64)/8) at (g*128 + r)*8.
// GEMM staging is a contiguous 8 KB copy; fragment read offset =
// g*1024 + r*8 with g = q + kk/8  ->  bank = 2r mod 32, conflict-free.

// ---------- helpers ----------

__device__ __forceinline__ uint32_t pack4_fp8(float a, float b, float c, float d) {
    int v = __builtin_amdgcn_cvt_pk_fp8_f32(a, b, 0, false);
    v = __builtin_amdgcn_cvt_pk_fp8_f32(c, d, v, true);
    return (uint32_t)v;
}

__device__ __forceinline__ void gload_lds16(const uint8_t* g, uint8_t* l) {
    __builtin_amdgcn_global_load_lds(
        (const __attribute__((address_space(1))) uint32_t*)g,
        (__attribute__((address_space(3))) uint32_t*)l,
        16, 0, 0);
}

__device__ __forceinline__ float scale_from_amax(float amax) {
    return FP8_MAX / fmaxf(amax, 1e-12f);
}

// ---------- kernel 0: init amax slots (ws is re-poisoned 0xAA each call) ----------

__global__ void init_amax_kernel(uint32_t* amax) {
    amax[0] = 0u;
    amax[1] = 0u;
}

// ---------- kernel 1: per-tensor amax ----------

__global__ void amax_kernel(const float* __restrict__ src, long n, uint32_t* out_bits) {
    long i = (long)blockIdx.x * blockDim.x + threadIdx.x;
    long stride = (long)gridDim.x * blockDim.x;
    const float4* s4 = (const float4*)src;
    long n4 = n >> 2;
    float m = 0.0f;
    for (long j = i; j < n4; j += stride) {
        float4 v = s4[j];
        m = fmaxf(m, fmaxf(fmaxf(fabsf(v.x), fabsf(v.y)), fmaxf(fabsf(v.z), fabsf(v.w))));
    }
    #pragma unroll
    for (int off = 32; off > 0; off >>= 1)
        m = fmaxf(m, __shfl_down(m, off, 64));
    __shared__ float smax[4];
    int wave = threadIdx.x >> 6;
    if ((threadIdx.x & 63) == 0) smax[wave] = m;
    __syncthreads();
    if (threadIdx.x == 0) {
        float bm = fmaxf(fmaxf(smax[0], smax[1]), fmaxf(smax[2], smax[3]));
        atomicMax(out_bits, __float_as_uint(bm));  // non-negative: bit order == value order
    }
}

// ---------- kernel 2: quantize x [M][K] -> tiled fp8 layout ----------

__global__ __launch_bounds__(256)
void quantX_kernel(const float* __restrict__ x, uint8_t* __restrict__ qx,
                   const uint32_t* __restrict__ amax_bits) {
    float scale = scale_from_amax(__uint_as_float(*amax_bits));
    long tileM = (long)blockIdx.y * 128;
    int kb = blockIdx.x * 64;
    uint8_t* outT = qx + ((size_t)blockIdx.y * (K_DIM / 64) + blockIdx.x) * 8192;
    int t = threadIdx.x;
    #pragma unroll
    for (int it = 0; it < 4; ++it) {
        int G = t + it * 256;        // granule index 0..1023
        int g = G >> 7;              // k-granule 0..7
        int rr = G & 127;            // row within tile
        const float4* p = (const float4*)(x + (tileM + rr) * K_DIM + kb + g * 8);
        float4 a = p[0];
        float4 b = p[1];
        uint2 o;
        o.x = pack4_fp8(a.x * scale, a.y * scale, a.z * scale, a.w * scale);
        o.y = pack4_fp8(b.x * scale, b.y * scale, b.z * scale, b.w * scale);
        *(uint2*)(outT + (size_t)G * 8) = o;   // lanes consecutive G -> coalesced
    }
}

// ---------- kernel 3: quantize + transpose w [K][N] -> tiled fp8 wT layout ----------

__global__ __launch_bounds__(256)
void quantW_kernel(const float* __restrict__ w, uint8_t* __restrict__ qwT,
                   const uint32_t* __restrict__ amax_bits) {
    float scale = scale_from_amax(__uint_as_float(*amax_bits));
    int n0 = blockIdx.y * 128;
    int kb = blockIdx.x * 64;
    uint8_t* outT = qwT + ((size_t)blockIdx.y * (K_DIM / 64) + blockIdx.x) * 8192;
    int t = threadIdx.x;
    #pragma unroll
    for (int it = 0; it < 4; ++it) {
        int G = t + it * 256;
        int g = G >> 7;
        int rr = G & 127;            // n within tile
        const float* col = w + (long)(kb + g * 8) * N_DIM + n0 + rr;
        float v[8];
        #pragma unroll
        for (int j = 0; j < 8; ++j)
            v[j] = col[(long)j * N_DIM] * scale;   // wave-coalesced per j
        uint2 o;
        o.x = pack4_fp8(v[0], v[1], v[2], v[3]);
        o.y = pack4_fp8(v[4], v[5], v[6], v[7]);
        *(uint2*)(outT + (size_t)G * 8) = o;
    }
}

// ---------- kernel 4: fp8 MFMA GEMM ----------

#define BM 128
#define BN 128
#define BK 64

__global__ __launch_bounds__(256)
void gemm_kernel(const uint8_t* __restrict__ qx, const uint8_t* __restrict__ qwT,
                 const float* __restrict__ bias, float* __restrict__ C,
                 const uint32_t* __restrict__ amax_bits) {
    float sx = scale_from_amax(__uint_as_float(amax_bits[0]));
    float sw = scale_from_amax(__uint_as_float(amax_bits[1]));
    float dq = 1.0f / (sx * sw);

    __shared__ __align__(16) uint8_t sA[BM * BK];   // granule-major tile
    __shared__ __align__(16) uint8_t sB[BN * BK];

    int tid = threadIdx.x;
    int wave = tid >> 6;
    int lane = tid & 63;

    long tileM = (long)blockIdx.y * BM;
    long tileN = (long)blockIdx.x * BN;

    const uint8_t* gA = qx + tileM * K_DIM;    // == tile(i,0) base
    const uint8_t* gB = qwT + tileN * K_DIM;

    floatx4 acc[4][4];
    #pragma unroll
    for (int i = 0; i < 4; ++i)
        #pragma unroll
        for (int j = 0; j < 4; ++j)
            acc[i][j] = (floatx4)0.0f;

    int waveM = (wave >> 1) * 64;
    int waveN = (wave & 1) * 64;
    int q = lane >> 4;                                // K-quad within MFMA step
    int aOff = q * 1024 + (waveM + (lane & 15)) * 8;  // granule (r, q) base
    int bOff = q * 1024 + (waveN + (lane & 15)) * 8;

    for (int k0 = 0; k0 < K_DIM; k0 += BK) {
        __syncthreads();
        const uint8_t* tA = gA + k0 * 128;     // contiguous 8 KB tile
        const uint8_t* tB = gB + k0 * 128;
        #pragma unroll
        for (int it = 0; it < 2; ++it) {
            int c = (tid + it * 256) * 16;
            gload_lds16(tA + c, sA + c);
            gload_lds16(tB + c, sB + c);
        }
        __syncthreads();

        #pragma unroll
        for (int kk = 0; kk < BK; kk += 32) {
            // granule g = q + kk/8 -> byte offset kk*128 (NOT kk*16 — r2 bug)
            long aF[4], bF[4];
            #pragma unroll
            for (int mi = 0; mi < 4; ++mi)
                aF[mi] = *(const long*)(sA + aOff + kk * 128 + mi * 128);
            #pragma unroll
            for (int ni = 0; ni < 4; ++ni)
                bF[ni] = *(const long*)(sB + bOff + kk * 128 + ni * 128);
            #pragma unroll
            for (int mi = 0; mi < 4; ++mi)
                #pragma unroll
                for (int ni = 0; ni < 4; ++ni)
                    acc[mi][ni] = __builtin_amdgcn_mfma_f32_16x16x32_fp8_fp8(
                        aF[mi], bF[ni], acc[mi][ni], 0, 0, 0);
        }
    }

    long colBase = tileN + waveN + (lane & 15);
    float bV[4];
    #pragma unroll
    for (int ni = 0; ni < 4; ++ni) bV[ni] = bias[colBase + ni * 16];

    #pragma unroll
    for (int mi = 0; mi < 4; ++mi) {
        #pragma unroll
        for (int r = 0; r < 4; ++r) {
            long row = tileM + waveM + mi * 16 + (lane >> 4) * 4 + r;
            float* crow = C + row * N_DIM;
            #pragma unroll
            for (int ni = 0; ni < 4; ++ni)
                crow[colBase + ni * 16] = acc[mi][ni][r] * dq + bV[ni];
        }
    }
}

// ---------- launch ----------

extern "C" void kernel_launch(void* const* d_in, const int* in_sizes, int n_in,
                              void* d_out, int out_size, void* d_ws, size_t ws_size,
                              hipStream_t stream) {
    const float* x = (const float*)d_in[0];     // [M][K]
    const float* w = (const float*)d_in[1];     // [K][N]
    const float* bias = (const float*)d_in[2];  // [N]
    float* out = (float*)d_out;                 // [M][N]

    uint32_t* amax = (uint32_t*)d_ws;           // [0]=amax_x, [1]=amax_w
    uint8_t* qx = (uint8_t*)d_ws + 256;
    uint8_t* qwT = qx + (size_t)M_DIM * K_DIM;

    init_amax_kernel<<<1, 64, 0, stream>>>(amax);
    amax_kernel<<<2048, 256, 0, stream>>>(x, (long)M_DIM * K_DIM, amax + 0);
    amax_kernel<<<2048, 256, 0, stream>>>(w, (long)K_DIM * N_DIM, amax + 1);
    quantX_kernel<<<dim3(K_DIM / 64, M_DIM / 128), 256, 0, stream>>>(x, qx, amax + 0);
    quantW_kernel<<<dim3(K_DIM / 64, N_DIM / 128), 256, 0, stream>>>(w, qwT, amax + 1);
    gemm_kernel<<<dim3(N_DIM / BN, M_DIM / BM), 256, 0, stream>>>(qx, qwT, bias, out, amax);
}

// Round 4
// 505.933 us; speedup vs baseline: 1.7535x; 1.1750x over previous
//
#include <hip/hip_runtime.h>
#include <stdint.h>

#define M_DIM 8192
#define K_DIM 4096
#define N_DIM 4096
#define FP8_MAX 448.0f

typedef float floatx16 __attribute__((ext_vector_type(16)));
typedef int intx8 __attribute__((ext_vector_type(8)));

// Tiled fp8 layout (v2, for 32x32x64 scaled MFMA):
//   tensor -> [128-row x 64-k] tiles of 8192 B; tile (i=row/128, b=k/64) at
//   (i*(K/64)+b)*8192  ==  base + row0*K + k0*128.
//   Within a tile, 16-byte granule (kq = (k%64)/16 sel within 32-k half? see below):
//     decompose row = mi*32 + r5 (mi in [0,4), r5 in [0,32))
//               k   = h*32 + kq*16 + j (h in {0,1}, kq in {0,1}, j in [0,16))
//     offset = kq*4096 + mi*1024 + (h*32 + r5)*16
//   MFMA 32x32x64 fragment: lane l holds row r5=l&31 of its 32-row group,
//   k-half h=l>>5, 32 consecutive k bytes. So fragment read = TWO ds_read_b128
//   at (kq*4096 + mi*1024) + 16*lane  -> lane-contiguous, conflict-free.
//   Staging remains a contiguous 8 KB copy (global_load_lds friendly).

// ---------- helpers ----------

__device__ __forceinline__ uint32_t pack4_fp8(float a, float b, float c, float d) {
    int v = __builtin_amdgcn_cvt_pk_fp8_f32(a, b, 0, false);
    v = __builtin_amdgcn_cvt_pk_fp8_f32(c, d, v, true);
    return (uint32_t)v;
}

__device__ __forceinline__ void gload_lds16(const uint8_t* g, uint8_t* l) {
    __builtin_amdgcn_global_load_lds(
        (const __attribute__((address_space(1))) uint32_t*)g,
        (__attribute__((address_space(3))) uint32_t*)l,
        16, 0, 0);
}

__device__ __forceinline__ float scale_from_amax(float amax) {
    return FP8_MAX / fmaxf(amax, 1e-12f);
}

// ---------- kernel 0: init amax slots ----------

__global__ void init_amax_kernel(uint32_t* amax) {
    amax[0] = 0u;
    amax[1] = 0u;
}

// ---------- kernel 1: fused per-tensor amax (x and w in one launch) ----------

__global__ __launch_bounds__(256)
void amax_kernel(const float* __restrict__ x, const float* __restrict__ w,
                 uint32_t* __restrict__ out_bits) {
    bool isX = blockIdx.x < 2048;
    const float* src = isX ? x : w;
    long n4 = (isX ? (long)M_DIM * K_DIM : (long)K_DIM * N_DIM) >> 2;
    int bid = isX ? blockIdx.x : blockIdx.x - 2048;
    int nb = isX ? 2048 : 1024;
    long i = (long)bid * blockDim.x + threadIdx.x;
    long stride = (long)nb * blockDim.x;
    const float4* s4 = (const float4*)src;
    float m = 0.0f;
    for (long j = i; j < n4; j += stride) {
        float4 v = s4[j];
        m = fmaxf(m, fmaxf(fmaxf(fabsf(v.x), fabsf(v.y)), fmaxf(fabsf(v.z), fabsf(v.w))));
    }
    #pragma unroll
    for (int off = 32; off > 0; off >>= 1)
        m = fmaxf(m, __shfl_down(m, off, 64));
    __shared__ float smax[4];
    int wave = threadIdx.x >> 6;
    if ((threadIdx.x & 63) == 0) smax[wave] = m;
    __syncthreads();
    if (threadIdx.x == 0) {
        float bm = fmaxf(fmaxf(smax[0], smax[1]), fmaxf(smax[2], smax[3]));
        atomicMax(out_bits + (isX ? 0 : 1), __float_as_uint(bm));
    }
}

// ---------- kernel 2: fused quantize x and w -> tiled fp8 layouts ----------
// blocks [0,4096): x tiles (M/128=64 x K/64=64); [4096,6144): wT tiles (N/128=32 x K/64=64)

__global__ __launch_bounds__(256)
void quant_kernel(const float* __restrict__ x, const float* __restrict__ w,
                  uint8_t* __restrict__ qx, uint8_t* __restrict__ qwT,
                  const uint32_t* __restrict__ amax_bits) {
    int b = blockIdx.x;
    if (b < 4096) {
        float scale = scale_from_amax(__uint_as_float(amax_bits[0]));
        int iy = b >> 6, ib = b & 63;
        const float* src = x + (long)iy * 128 * K_DIM;
        uint8_t* outT = qx + (size_t)b * 8192;
        int kb = ib * 64;
        #pragma unroll
        for (int it = 0; it < 2; ++it) {
            int G = threadIdx.x + it * 256;
            int kq = G >> 8, rem = G & 255;
            int mi = rem >> 6, h = (rem >> 5) & 1, r5 = rem & 31;
            const float4* p = (const float4*)(src + (long)(mi * 32 + r5) * K_DIM
                                              + kb + h * 32 + kq * 16);
            float4 v0 = p[0], v1 = p[1], v2 = p[2], v3 = p[3];
            uint4 o;
            o.x = pack4_fp8(v0.x * scale, v0.y * scale, v0.z * scale, v0.w * scale);
            o.y = pack4_fp8(v1.x * scale, v1.y * scale, v1.z * scale, v1.w * scale);
            o.z = pack4_fp8(v2.x * scale, v2.y * scale, v2.z * scale, v2.w * scale);
            o.w = pack4_fp8(v3.x * scale, v3.y * scale, v3.z * scale, v3.w * scale);
            *(uint4*)(outT + (size_t)G * 16) = o;   // consecutive G -> coalesced
        }
    } else {
        float scale = scale_from_amax(__uint_as_float(amax_bits[1]));
        b -= 4096;
        int iy = b >> 6, ib = b & 63;     // iy = n-tile
        int n0 = iy * 128, kb = ib * 64;
        uint8_t* outT = qwT + (size_t)b * 8192;
        #pragma unroll
        for (int it = 0; it < 2; ++it) {
            int G = threadIdx.x + it * 256;
            int kq = G >> 8, rem = G & 255;
            int mi = rem >> 6, h = (rem >> 5) & 1, r5 = rem & 31;
            int n = n0 + mi * 32 + r5;
            const float* col = w + (long)(kb + h * 32 + kq * 16) * N_DIM + n;
            float v[16];
            #pragma unroll
            for (int j = 0; j < 16; ++j)
                v[j] = col[(long)j * N_DIM] * scale;   // wave-coalesced per j
            uint4 o;
            o.x = pack4_fp8(v[0], v[1], v[2], v[3]);
            o.y = pack4_fp8(v[4], v[5], v[6], v[7]);
            o.z = pack4_fp8(v[8], v[9], v[10], v[11]);
            o.w = pack4_fp8(v[12], v[13], v[14], v[15]);
            *(uint4*)(outT + (size_t)G * 16) = o;
        }
    }
}

// ---------- kernel 3: MX-scaled fp8 MFMA GEMM (unit scales, 2x fp8 rate) ----------

#define BM 128
#define BN 128
#define BK 64
#define UNIT_SCALE 0x7F7F7F7F   // e8m0 0x7F = 2^0 = 1.0 per 32-elem block

__global__ __launch_bounds__(256)
void gemm_kernel(const uint8_t* __restrict__ qx, const uint8_t* __restrict__ qwT,
                 const float* __restrict__ bias, float* __restrict__ C,
                 const uint32_t* __restrict__ amax_bits) {
    float sx = scale_from_amax(__uint_as_float(amax_bits[0]));
    float sw = scale_from_amax(__uint_as_float(amax_bits[1]));
    float dq = 1.0f / (sx * sw);

    __shared__ __align__(16) uint8_t sA[BM * BK];
    __shared__ __align__(16) uint8_t sB[BN * BK];

    int tid = threadIdx.x;
    int wave = tid >> 6;
    int lane = tid & 63;
    int wm = wave >> 1;            // 2x2 wave grid; each wave owns 64x64 (2x2 of 32x32)
    int wn = wave & 1;

    long tileM = (long)blockIdx.y * BM;
    long tileN = (long)blockIdx.x * BN;

    const uint8_t* gA = qx + tileM * K_DIM;    // tile-row base (tiles contiguous along k)
    const uint8_t* gB = qwT + tileN * K_DIM;

    floatx16 acc[2][2];
    #pragma unroll
    for (int i = 0; i < 2; ++i)
        #pragma unroll
        for (int j = 0; j < 2; ++j)
            acc[i][j] = (floatx16)0.0f;

    int l16 = lane * 16;

    for (int k0 = 0; k0 < K_DIM; k0 += BK) {
        __syncthreads();
        const uint8_t* tA = gA + k0 * 128;     // contiguous 8 KB tile
        const uint8_t* tB = gB + k0 * 128;
        #pragma unroll
        for (int it = 0; it < 2; ++it) {
            int c = (tid + it * 256) * 16;
            gload_lds16(tA + c, sA + c);
            gload_lds16(tB + c, sB + c);
        }
        __syncthreads();

        // fragment reads: kq halves at +0 / +4096; lane-contiguous b128 reads
        union Frag { intx8 v; int4 q[2]; };
        Frag fa[2], fb[2];
        #pragma unroll
        for (int mi = 0; mi < 2; ++mi) {
            int ab = ((wm * 2 + mi) << 10) + l16;
            fa[mi].q[0] = *(const int4*)(sA + ab);
            fa[mi].q[1] = *(const int4*)(sA + 4096 + ab);
            int bb = ((wn * 2 + mi) << 10) + l16;
            fb[mi].q[0] = *(const int4*)(sB + bb);
            fb[mi].q[1] = *(const int4*)(sB + 4096 + bb);
        }
        #pragma unroll
        for (int mi = 0; mi < 2; ++mi)
            #pragma unroll
            for (int ni = 0; ni < 2; ++ni)
                acc[mi][ni] = __builtin_amdgcn_mfma_scale_f32_32x32x64_f8f6f4(
                    fa[mi].v, fb[ni].v, acc[mi][ni],
                    0, 0,                      // cbsz=fp8(e4m3), blgp=fp8(e4m3)
                    0, UNIT_SCALE,             // scale A: byte-sel 0, 1.0
                    0, UNIT_SCALE);            // scale B: byte-sel 0, 1.0
    }

    // epilogue: 32x32 C/D layout: col = lane&31, row = (reg&3) + 8*(reg>>2) + 4*(lane>>5)
    int cn = lane & 31;
    int h4 = (lane >> 5) * 4;
    #pragma unroll
    for (int ni = 0; ni < 2; ++ni) {
        long col = tileN + wn * 64 + ni * 32 + cn;
        float bv = bias[col];
        #pragma unroll
        for (int mi = 0; mi < 2; ++mi) {
            long rowBase = tileM + wm * 64 + mi * 32 + h4;
            floatx16 a = acc[mi][ni];
            #pragma unroll
            for (int rg = 0; rg < 4; ++rg) {
                long row = rowBase + 8 * rg;
                #pragma unroll
                for (int rr = 0; rr < 4; ++rr)
                    C[(row + rr) * N_DIM + col] = a[rg * 4 + rr] * dq + bv;
            }
        }
    }
}

// ---------- launch ----------

extern "C" void kernel_launch(void* const* d_in, const int* in_sizes, int n_in,
                              void* d_out, int out_size, void* d_ws, size_t ws_size,
                              hipStream_t stream) {
    const float* x = (const float*)d_in[0];     // [M][K]
    const float* w = (const float*)d_in[1];     // [K][N]
    const float* bias = (const float*)d_in[2];  // [N]
    float* out = (float*)d_out;                 // [M][N]

    uint32_t* amax = (uint32_t*)d_ws;           // [0]=amax_x, [1]=amax_w
    uint8_t* qx = (uint8_t*)d_ws + 256;
    uint8_t* qwT = qx + (size_t)M_DIM * K_DIM;

    init_amax_kernel<<<1, 64, 0, stream>>>(amax);
    amax_kernel<<<3072, 256, 0, stream>>>(x, w, amax);
    quant_kernel<<<6144, 256, 0, stream>>>(x, w, qx, qwT, amax);
    gemm_kernel<<<dim3(N_DIM / BN, M_DIM / BM), 256, 0, stream>>>(qx, qwT, bias, out, amax);
}